// Round 1
// 518.723 us; speedup vs baseline: 1.0237x; 1.0237x over previous
//
#include <hip/hip_runtime.h>
#include <cstdint>

// ---------------------------------------------------------------------------
// GCNRecommender round 4:
//  - x fp32->bf16 conversion folded into GEMM L1 A-staging (AF32 template)
//  - L4 GEMM + bias + LayerNorm(64) + ELU fused in epilogue (F1 scratch gone)
//  - scan2 merged into scan3 (per-block bsums reduce)
//  - deg zeroing merged into weight-convert kernel
//  - CSR fill cursor pre-seeded with rowptr; coef on-the-fly from dinv
// ---------------------------------------------------------------------------

#define LN_EPS 1e-5f

typedef __attribute__((ext_vector_type(8))) short bf16x8;
typedef __attribute__((ext_vector_type(4))) float f32x4;

static __device__ __forceinline__ ushort f2bf(float f) {
  union { float f; uint u; } c; c.f = f;
  uint u = c.u;
  return (ushort)((u + 0x7fffu + ((u >> 16) & 1u)) >> 16);  // RNE
}
static __device__ __forceinline__ float bf2f(ushort h) {
  union { uint u; float f; } c; c.u = (uint)h << 16;
  return c.f;
}

// ---------------- CSR build ----------------

__global__ void deg_kernel(const int* __restrict__ dst, int* __restrict__ deg, int E) {
  int e = blockIdx.x * blockDim.x + threadIdx.x;
  if (e < E) atomicAdd(&deg[dst[e]], 1);
}

__global__ void scan1_kernel(const int* __restrict__ deg, int* __restrict__ excl,
                             int* __restrict__ bsums, float* __restrict__ dinv, int N) {
  __shared__ int s[256];
  int tid = threadIdx.x;
  int i = blockIdx.x * 256 + tid;
  int v = (i < N) ? deg[i] : 0;
  s[tid] = v;
  __syncthreads();
  for (int o = 1; o < 256; o <<= 1) {
    int t = (tid >= o) ? s[tid - o] : 0;
    __syncthreads();
    if (tid >= o) s[tid] += t;
    __syncthreads();
  }
  if (i < N) {
    excl[i] = s[tid] - v;
    dinv[i] = rsqrtf((float)v + 1.0f);  // +1 self-loop
  }
  if (tid == 255) bsums[blockIdx.x] = s[tid];
}

// finalize rowptr (+ block-sum offset computed in-kernel) and seed fill cursor
__global__ void scan23_kernel(int* __restrict__ rowptr, int* __restrict__ fill,
                              const int* __restrict__ bsums, int N, int Etotal, int nb) {
  __shared__ int sh[256];
  const int tid = threadIdx.x;
  const int bix = blockIdx.x;
  // sum of bsums[0..bix-1]  (nb <= 256)
  int v = (tid < bix && tid < nb) ? bsums[tid] : 0;
  sh[tid] = v;
  __syncthreads();
  for (int o = 128; o > 0; o >>= 1) {
    if (tid < o) sh[tid] += sh[tid + o];
    __syncthreads();
  }
  const int off = sh[0];
  int i = bix * 256 + tid;
  if (i < N) {
    int r = rowptr[i] + off;
    rowptr[i] = r;
    fill[i] = r;
  } else if (i == N) {
    rowptr[N] = Etotal;
  }
}

__global__ void fill_kernel(const int* __restrict__ src, const int* __restrict__ dst,
                            int* __restrict__ fill, int* __restrict__ srcs, int E) {
  int e = blockIdx.x * blockDim.x + threadIdx.x;
  if (e >= E) return;
  int idx = atomicAdd(&fill[dst[e]], 1);
  srcs[idx] = src[e];
}

// ---------------- prep: weight convert + deg zero ----------------

struct WConvArgs {
  const float* w[5];
  ushort* wt[5];
  int K[5], N[5];
  int off[6];
};

// W[K][N] fp32 -> Wt[N][K] bf16 (all 5 mats) + zero deg[] in the same launch
__global__ void prep_kernel(WConvArgs a, int total, int* __restrict__ deg, int Nn) {
  int i = blockIdx.x * blockDim.x + threadIdx.x;
  if (i < Nn) deg[i] = 0;
  if (i >= total) return;
  int m = 0;
  while (i >= a.off[m + 1]) m++;
  int j = i - a.off[m];
  int k = j / a.N[m], n = j - k * a.N[m];
  a.wt[m][(size_t)n * a.K[m] + k] = f2bf(a.w[m][j]);
}

// ---------------- bf16 MFMA GEMM ----------------
// C[M][N] = A[M][K] @ Bt[N][K]^T (+ bias). K % 32 == 0.
// AF32: A is fp32, converted to bf16 during LDS staging.
// EMODE: 0 = fp32 out, 1 = bf16 out, 2 = fused bias+LN(64)+ELU -> bf16 (N==64)
#define TBM 128
#define TBN 128
#define TBK 32
#define LDK 40

template <int AF32, int EMODE>
__global__ __launch_bounds__(256, 2) void mfma_gemm_kernel(
    const void* __restrict__ A, const ushort* __restrict__ Bt,
    const float* __restrict__ bias, const float* __restrict__ gamma,
    const float* __restrict__ beta, void* __restrict__ Cout,
    int M, int N, int K) {
  __shared__ ushort As[TBM][LDK];
  __shared__ ushort Bs[TBN][LDK];
  const int tid = threadIdx.x;
  const int lane = tid & 63;
  const int w = tid >> 6;
  const int wm = w & 1, wn = w >> 1;
  const int quad = lane >> 4, l16 = lane & 15;
  const int rowBase = blockIdx.y * TBM;
  const int colBase = blockIdx.x * TBN;

  f32x4 acc[4][4] = {};
  const int lr = tid >> 2;
  const int lk = (tid & 3) * 8;

  for (int k0 = 0; k0 < K; k0 += TBK) {
#pragma unroll
    for (int h = 0; h < 2; h++) {
      int r = lr + h * 64;
      int grow = rowBase + r;
      if (AF32) {
        const float* Af = (const float*)A;
        float4 v0 = make_float4(0.f, 0.f, 0.f, 0.f), v1 = v0;
        if (grow < M) {
          const float* ap = Af + (size_t)grow * K + k0 + lk;
          v0 = *(const float4*)ap;
          v1 = *(const float4*)(ap + 4);
        }
        uint4 wv;
        wv.x = (uint)f2bf(v0.x) | ((uint)f2bf(v0.y) << 16);
        wv.y = (uint)f2bf(v0.z) | ((uint)f2bf(v0.w) << 16);
        wv.z = (uint)f2bf(v1.x) | ((uint)f2bf(v1.y) << 16);
        wv.w = (uint)f2bf(v1.z) | ((uint)f2bf(v1.w) << 16);
        *(uint4*)&As[r][lk] = wv;
      } else {
        const ushort* Ab = (const ushort*)A;
        uint4 va = make_uint4(0, 0, 0, 0);
        if (grow < M) va = *(const uint4*)(Ab + (size_t)grow * K + k0 + lk);
        *(uint4*)&As[r][lk] = va;
      }
      int gcol = colBase + r;
      uint4 vb = make_uint4(0, 0, 0, 0);
      if (gcol < N) vb = *(const uint4*)(Bt + (size_t)gcol * K + k0 + lk);
      *(uint4*)&Bs[r][lk] = vb;
    }
    __syncthreads();
    bf16x8 af[4], bfr[4];
#pragma unroll
    for (int i = 0; i < 4; i++) {
      af[i]  = *(const bf16x8*)&As[wm * 64 + i * 16 + l16][quad * 8];
      bfr[i] = *(const bf16x8*)&Bs[wn * 64 + i * 16 + l16][quad * 8];
    }
#pragma unroll
    for (int i = 0; i < 4; i++)
#pragma unroll
      for (int j = 0; j < 4; j++)
        acc[i][j] = __builtin_amdgcn_mfma_f32_16x16x32_bf16(af[i], bfr[j], acc[i][j], 0, 0, 0);
    __syncthreads();
  }

  if constexpr (EMODE == 2) {
    // fused bias + LayerNorm(64) + ELU -> bf16. Requires N == 64.
    // Each row's 64 cols live in one wave (wn==0): cols = j*16 + l16.
    if (wn != 0) return;
    const int rowB = rowBase + wm * 64;
#pragma unroll
    for (int i = 0; i < 4; i++) {
#pragma unroll
      for (int r = 0; r < 4; r++) {
        int row = rowB + i * 16 + quad * 4 + r;
        float v[4];
        float s = 0.f;
#pragma unroll
        for (int j = 0; j < 4; j++) {
          int col = j * 16 + l16;
          v[j] = acc[i][j][r] + bias[col];
          s += v[j];
        }
#pragma unroll
        for (int o = 8; o >= 1; o >>= 1) s += __shfl_xor(s, o, 16);
        float mean = s * (1.0f / 64.0f);
        float q = 0.f;
#pragma unroll
        for (int j = 0; j < 4; j++) {
          float d = v[j] - mean;
          q += d * d;
        }
#pragma unroll
        for (int o = 8; o >= 1; o >>= 1) q += __shfl_xor(q, o, 16);
        float rstd = rsqrtf(q * (1.0f / 64.0f) + LN_EPS);
        if (row < M) {
#pragma unroll
          for (int j = 0; j < 4; j++) {
            int col = j * 16 + l16;
            float y = (v[j] - mean) * rstd * gamma[col] + beta[col];
            y = (y > 0.f) ? y : expm1f(y);
            ((ushort*)Cout)[(size_t)row * 64 + col] = f2bf(y);
          }
        }
      }
    }
    return;
  } else {
#pragma unroll
    for (int i = 0; i < 4; i++) {
      int row0 = rowBase + wm * 64 + i * 16 + quad * 4;
#pragma unroll
      for (int j = 0; j < 4; j++) {
        int col = colBase + wn * 64 + j * 16 + l16;
        if (col >= N) continue;
        float bv = bias ? bias[col] : 0.f;
#pragma unroll
        for (int r = 0; r < 4; r++) {
          int row = row0 + r;
          if (row >= M) continue;
          float vv = acc[i][j][r] + bv;
          if (EMODE == 1) ((ushort*)Cout)[(size_t)row * N + col] = f2bf(vv);
          else            ((float*)Cout)[(size_t)row * N + col] = vv;
        }
      }
    }
  }
}

// ---------------- aggregation kernels, F=128 bf16 ----------------
// Edge coef computed on the fly: c = dinv[src] * dinv[n].
// 1 wave per node, lane f handles features (2f, 2f+1) packed in one uint.

// Plain agg (no bias, no LN) -> bf16  [used before L2 GEMM]
__global__ __launch_bounds__(256) void agg_kernel(
    const ushort* __restrict__ hb, const int* __restrict__ rowptr,
    const int* __restrict__ srcs, const float* __restrict__ dinv,
    uint* __restrict__ out, int Nn) {
  const int wave = threadIdx.x >> 6;
  const int n = blockIdx.x * 4 + wave;
  if (n >= Nn) return;
  const int f = threadIdx.x & 63;
  const uint* h32 = (const uint*)hb;
  const float di = dinv[n];
  uint self = h32[(size_t)n * 64 + f];
  float a0 = bf2f((ushort)(self & 0xffffu)) * di * di;
  float a1 = bf2f((ushort)(self >> 16)) * di * di;
  int i = rowptr[n];
  const int e = rowptr[n + 1];
  for (; i + 3 < e; i += 4) {
    int s0 = srcs[i], s1 = srcs[i + 1], s2 = srcs[i + 2], s3 = srcs[i + 3];
    float c0 = dinv[s0] * di, c1 = dinv[s1] * di, c2 = dinv[s2] * di, c3 = dinv[s3] * di;
    uint v0 = h32[(size_t)s0 * 64 + f];
    uint v1 = h32[(size_t)s1 * 64 + f];
    uint v2 = h32[(size_t)s2 * 64 + f];
    uint v3 = h32[(size_t)s3 * 64 + f];
    a0 += c0 * bf2f((ushort)(v0 & 0xffffu)) + c1 * bf2f((ushort)(v1 & 0xffffu)) +
          c2 * bf2f((ushort)(v2 & 0xffffu)) + c3 * bf2f((ushort)(v3 & 0xffffu));
    a1 += c0 * bf2f((ushort)(v0 >> 16)) + c1 * bf2f((ushort)(v1 >> 16)) +
          c2 * bf2f((ushort)(v2 >> 16)) + c3 * bf2f((ushort)(v3 >> 16));
  }
  for (; i < e; i++) {
    int s = srcs[i];
    float c = dinv[s] * di;
    uint v = h32[(size_t)s * 64 + f];
    a0 += c * bf2f((ushort)(v & 0xffffu));
    a1 += c * bf2f((ushort)(v >> 16));
  }
  out[(size_t)n * 64 + f] = (uint)f2bf(a0) | ((uint)f2bf(a1) << 16);
}

// Fused agg + bias + LayerNorm + ELU -> bf16  [layers 1 and 3]
__global__ __launch_bounds__(256) void agg_ln_kernel(
    const ushort* __restrict__ hb, const int* __restrict__ rowptr,
    const int* __restrict__ srcs, const float* __restrict__ dinv,
    const float* __restrict__ bias, const float* __restrict__ g,
    const float* __restrict__ be, uint* __restrict__ out, int Nn) {
  const int wave = threadIdx.x >> 6;
  const int n = blockIdx.x * 4 + wave;
  if (n >= Nn) return;
  const int f = threadIdx.x & 63;
  const uint* h32 = (const uint*)hb;
  const float di = dinv[n];
  uint self = h32[(size_t)n * 64 + f];
  float2 bv = ((const float2*)bias)[f];
  float a0 = bf2f((ushort)(self & 0xffffu)) * di * di + bv.x;
  float a1 = bf2f((ushort)(self >> 16)) * di * di + bv.y;
  int i = rowptr[n];
  const int e = rowptr[n + 1];
  for (; i + 3 < e; i += 4) {
    int s0 = srcs[i], s1 = srcs[i + 1], s2 = srcs[i + 2], s3 = srcs[i + 3];
    float c0 = dinv[s0] * di, c1 = dinv[s1] * di, c2 = dinv[s2] * di, c3 = dinv[s3] * di;
    uint v0 = h32[(size_t)s0 * 64 + f];
    uint v1 = h32[(size_t)s1 * 64 + f];
    uint v2 = h32[(size_t)s2 * 64 + f];
    uint v3 = h32[(size_t)s3 * 64 + f];
    a0 += c0 * bf2f((ushort)(v0 & 0xffffu)) + c1 * bf2f((ushort)(v1 & 0xffffu)) +
          c2 * bf2f((ushort)(v2 & 0xffffu)) + c3 * bf2f((ushort)(v3 & 0xffffu));
    a1 += c0 * bf2f((ushort)(v0 >> 16)) + c1 * bf2f((ushort)(v1 >> 16)) +
          c2 * bf2f((ushort)(v2 >> 16)) + c3 * bf2f((ushort)(v3 >> 16));
  }
  for (; i < e; i++) {
    int s = srcs[i];
    float c = dinv[s] * di;
    uint v = h32[(size_t)s * 64 + f];
    a0 += c * bf2f((ushort)(v & 0xffffu));
    a1 += c * bf2f((ushort)(v >> 16));
  }
  // LayerNorm over 128 features (2 per lane, 64 lanes) + ELU
  float s = a0 + a1;
#pragma unroll
  for (int o = 32; o >= 1; o >>= 1) s += __shfl_xor(s, o);
  float mean = s * (1.0f / 128.0f);
  float d0 = a0 - mean, d1 = a1 - mean;
  float q = d0 * d0 + d1 * d1;
#pragma unroll
  for (int o = 32; o >= 1; o >>= 1) q += __shfl_xor(q, o);
  float rstd = rsqrtf(q * (1.0f / 128.0f) + LN_EPS);
  float2 gv = ((const float2*)g)[f];
  float2 bev = ((const float2*)be)[f];
  float y0 = d0 * rstd * gv.x + bev.x;
  float y1 = d1 * rstd * gv.y + bev.y;
  y0 = (y0 > 0.f) ? y0 : expm1f(y0);
  y1 = (y1 > 0.f) ? y1 : expm1f(y1);
  out[(size_t)n * 64 + f] = (uint)f2bf(y0) | ((uint)f2bf(y1) << 16);
}

// ---------------- LayerNorm + ELU (standalone, L2 only) ----------------
template <int F, bool IN_BF16>
__global__ __launch_bounds__(F) void ln_elu_kernel(const void* __restrict__ xin,
                                                   const float* __restrict__ g,
                                                   const float* __restrict__ be,
                                                   ushort* __restrict__ out) {
  constexpr int NW = (F + 63) / 64;
  __shared__ float sb[NW];
  const int row = blockIdx.x;
  const int f = threadIdx.x;
  float v;
  if (IN_BF16) v = bf2f(((const ushort*)xin)[(size_t)row * F + f]);
  else         v = ((const float*)xin)[(size_t)row * F + f];
  float s = v;
#pragma unroll
  for (int o = 32; o >= 1; o >>= 1) s += __shfl_xor(s, o);
  float mean;
  if constexpr (NW == 1) {
    mean = s * (1.0f / F);
  } else {
    if ((f & 63) == 0) sb[f >> 6] = s;
    __syncthreads();
    float t = 0.f;
#pragma unroll
    for (int w2 = 0; w2 < NW; w2++) t += sb[w2];
    mean = t * (1.0f / F);
    __syncthreads();
  }
  float d = v - mean;
  float q = d * d;
#pragma unroll
  for (int o = 32; o >= 1; o >>= 1) q += __shfl_xor(q, o);
  float var;
  if constexpr (NW == 1) {
    var = q * (1.0f / F);
  } else {
    if ((f & 63) == 0) sb[f >> 6] = q;
    __syncthreads();
    float t = 0.f;
#pragma unroll
    for (int w2 = 0; w2 < NW; w2++) t += sb[w2];
    var = t * (1.0f / F);
  }
  float y = d * rsqrtf(var + LN_EPS) * g[f] + be[f];
  out[(size_t)row * F + f] = f2bf((y > 0.f) ? y : expm1f(y));
}

// ---------------- host ----------------

extern "C" void kernel_launch(void* const* d_in, const int* in_sizes, int n_in,
                              void* d_out, int out_size, void* d_ws, size_t ws_size,
                              hipStream_t stream) {
  const float* x   = (const float*)d_in[0];
  const int*   ei  = (const int*)d_in[1];
  const float* W1  = (const float*)d_in[2];
  const float* b1  = (const float*)d_in[3];
  const float* g1  = (const float*)d_in[4];
  const float* be1 = (const float*)d_in[5];
  const float* W2  = (const float*)d_in[6];
  const float* b2  = (const float*)d_in[7];
  const float* g2  = (const float*)d_in[8];
  const float* be2 = (const float*)d_in[9];
  const float* W3  = (const float*)d_in[10];
  const float* b3  = (const float*)d_in[11];
  const float* g3  = (const float*)d_in[12];
  const float* be3 = (const float*)d_in[13];
  const float* Wl1 = (const float*)d_in[14];
  const float* bl1 = (const float*)d_in[15];
  const float* g4  = (const float*)d_in[16];
  const float* be4 = (const float*)d_in[17];
  const float* Wl2 = (const float*)d_in[18];
  const float* bl2 = (const float*)d_in[19];

  const int N = in_sizes[0] / 128;  // 50000
  const int E = in_sizes[1] / 2;    // 800000
  const int* esrc = ei;
  const int* edst = ei + E;

  // workspace layout
  char* p = (char*)d_ws;
  ushort* Pb = (ushort*)p;            p += (size_t)N * 256 * 2;  // bf16 act buf
  ushort* Qb = (ushort*)p;            p += (size_t)N * 256 * 2;
  ushort* W1t = (ushort*)p;           p += 128 * 128 * 2;
  ushort* W2t = (ushort*)p;           p += 128 * 256 * 2;
  ushort* W3t = (ushort*)p;           p += 256 * 128 * 2;
  ushort* Wl1t = (ushort*)p;          p += 128 * 64 * 2;
  ushort* Wl2t = (ushort*)p;          p += 64 * 500 * 2;
  int*   srcs  = (int*)p;             p += (size_t)E * 4;
  int*   deg   = (int*)p;             p += (size_t)N * 4;
  float* dinv  = (float*)p;           p += (size_t)N * 4;
  int*   rowptr= (int*)p;             p += (size_t)(N + 2) * 4;
  int*   fill  = (int*)p;             p += (size_t)N * 4;
  int*   bsums = (int*)p;             p += 256 * 4;

  const int nb = (N + 255) / 256;
  const int eb = (E + 255) / 256;

  // ---- prep: weight convert + deg zero (one launch) ----
  WConvArgs wa;
  wa.w[0] = W1;  wa.wt[0] = W1t;  wa.K[0] = 128; wa.N[0] = 128;
  wa.w[1] = W2;  wa.wt[1] = W2t;  wa.K[1] = 128; wa.N[1] = 256;
  wa.w[2] = W3;  wa.wt[2] = W3t;  wa.K[2] = 256; wa.N[2] = 128;
  wa.w[3] = Wl1; wa.wt[3] = Wl1t; wa.K[3] = 128; wa.N[3] = 64;
  wa.w[4] = Wl2; wa.wt[4] = Wl2t; wa.K[4] = 64;  wa.N[4] = 500;
  wa.off[0] = 0;
  for (int m = 0; m < 5; m++) wa.off[m + 1] = wa.off[m] + wa.K[m] * wa.N[m];
  int wtotal = wa.off[5];
  int ptotal = wtotal > N ? wtotal : N;
  prep_kernel<<<(ptotal + 255) / 256, 256, 0, stream>>>(wa, wtotal, deg, N);

  // ---- CSR build ----
  deg_kernel<<<eb, 256, 0, stream>>>(edst, deg, E);
  scan1_kernel<<<nb, 256, 0, stream>>>(deg, rowptr, bsums, dinv, N);
  scan23_kernel<<<(N + 256) / 256, 256, 0, stream>>>(rowptr, fill, bsums, N, E, nb);
  fill_kernel<<<eb, 256, 0, stream>>>(esrc, edst, fill, srcs, E);

  const int ab = (N + 3) / 4;
  auto grid_of = [&](int M, int Nn) {
    return dim3((Nn + TBN - 1) / TBN, (M + TBM - 1) / TBM);
  };

  // L1: h1 = elu(LN(Agg(x@W1) + b1))   -- x converted fp32->bf16 in-GEMM
  mfma_gemm_kernel<1, 1><<<grid_of(N, 128), 256, 0, stream>>>(
      x, W1t, nullptr, nullptr, nullptr, Pb, N, 128, 128);
  agg_ln_kernel<<<ab, 256, 0, stream>>>(Pb, rowptr, srcs, dinv, b1, g1, be1, (uint*)Qb, N);

  // L2: h2 = elu(LN(Agg(h1)@W2 + b2))
  agg_kernel<<<ab, 256, 0, stream>>>(Qb, rowptr, srcs, dinv, (uint*)Pb, N);
  mfma_gemm_kernel<0, 1><<<grid_of(N, 256), 256, 0, stream>>>(
      Pb, W2t, b2, nullptr, nullptr, Qb, N, 256, 128);
  ln_elu_kernel<256, true><<<N, 256, 0, stream>>>(Qb, g2, be2, Pb);

  // L3: h3 = elu(LN(Agg(h2@W3) + b3))
  mfma_gemm_kernel<0, 1><<<grid_of(N, 128), 256, 0, stream>>>(
      Pb, W3t, nullptr, nullptr, nullptr, Qb, N, 128, 256);
  agg_ln_kernel<<<ab, 256, 0, stream>>>(Qb, rowptr, srcs, dinv, b3, g3, be3, (uint*)Pb, N);

  // L4: h4 = elu(LN(h3@Wl1 + bl1))  -- LN+ELU fused in GEMM epilogue
  mfma_gemm_kernel<0, 2><<<grid_of(N, 64), 256, 0, stream>>>(
      Pb, Wl1t, bl1, g4, be4, Qb, N, 64, 128);

  // L5: out = h4@Wl2 + bl2
  mfma_gemm_kernel<0, 0><<<grid_of(N, 500), 256, 0, stream>>>(
      Qb, Wl2t, bl2, nullptr, nullptr, d_out, N, 500, 64);
}